// Round 3
// baseline (407.499 us; speedup 1.0000x reference)
//
#include <hip/hip_runtime.h>
#include <hip/hip_bf16.h>
#include <stdint.h>

#define K_DIM 512
#define N_DIM 512
#define BM 64

typedef __bf16 bf16x8 __attribute__((ext_vector_type(8)));
typedef float floatx4 __attribute__((ext_vector_type(4)));

__device__ __forceinline__ bf16x8 cvt8(float4 a, float4 b) {
    bf16x8 r;
    r[0] = (__bf16)a.x; r[1] = (__bf16)a.y; r[2] = (__bf16)a.z; r[3] = (__bf16)a.w;
    r[4] = (__bf16)b.x; r[5] = (__bf16)b.y; r[6] = (__bf16)b.z; r[7] = (__bf16)b.w;
    return r;
}

// Pre-convert W [N,K] fp32 -> fragment-linear bf16:
// wf[((ntg*16+kc)*64 + lane)*8 + j] = W[ntg*16+(lane&15)][kc*32+(lane>>4)*8+j]
__global__ __launch_bounds__(512) void wconv_kernel(const float* __restrict__ w,
                                                    __bf16* __restrict__ wf) {
    int t = blockIdx.x * 512 + threadIdx.x;     // 0..32767
    int lane = t & 63, slot = t >> 6;           // slot = ntg*16+kc
    int n = ((slot >> 4) << 4) + (lane & 15);
    int k = ((slot & 15) << 5) + ((lane >> 4) << 3);
    const float* src = w + (size_t)n * K_DIM + k;
    float4 f0 = *(const float4*)src;
    float4 f1 = *(const float4*)(src + 4);
    *(bf16x8*)(wf + (size_t)t * 8) = cvt8(f0, f1);
}

// Persistent pipelined GEMM: 1024 threads = 16 waves, each wave owns 64x32 of the
// 64x512 block tile. Single 64KB fragment-linear LDS buffer; half-tile (kc 0..7 /
// 8..15) register-bridged double "buffer": loads for tile t+1 issued before compute
// of tile t, LDS writes land after the barrier that retires reads of that half.
template <bool USE_WF>
__global__ __launch_bounds__(1024, 4) void gemm_kernel(
    const float* __restrict__ x, const float* __restrict__ xscale,
    const __bf16* __restrict__ wf, const float* __restrict__ w,
    const float* __restrict__ wscale, float* __restrict__ out,
    int ntiles, int tilesPerBlock)
{
    __shared__ __bf16 lds[BM * K_DIM];   // 64 KiB: [idx=rt*16+kc][lane][8 bf16]
    const int t = threadIdx.x;
    const int lane = t & 63;
    const int wid = t >> 6;              // 0..15
    const int laneR = lane & 15;
    const int laneK = (lane >> 4) << 3;  // 0,8,16,24
    const int colb = wid * 32;

    const int tile0 = blockIdx.x * tilesPerBlock;
    if (tile0 >= ntiles) return;
    const int tileEnd = (tile0 + tilesPerBlock < ntiles) ? (tile0 + tilesPerBlock) : ntiles;

    // ---- prologue: stage full tile0 (4 slots per wave) ----
    {
        float4 f[8];
        #pragma unroll
        for (int p = 0; p < 4; ++p) {
            int slot = wid * 4 + p;          // 0..63 = rt*16+kc
            int rt = slot >> 4, kc = slot & 15;
            const float* src = x + (size_t)(tile0 * BM + rt * 16 + laneR) * K_DIM + kc * 32 + laneK;
            f[2 * p]     = *(const float4*)src;
            f[2 * p + 1] = *(const float4*)(src + 4);
        }
        #pragma unroll
        for (int p = 0; p < 4; ++p) {
            int slot = wid * 4 + p;
            *(bf16x8*)&lds[slot * 512 + lane * 8] = cvt8(f[2 * p], f[2 * p + 1]);
        }
    }
    __syncthreads();

    floatx4 acc[4][2];

    for (int tile = tile0; tile < tileEnd; ++tile) {
        const int rowb = tile * BM;
        const bool pf = (tile + 1 < tileEnd);
        float4 r0[4], r1[4];

        // issue global loads for half0 (kc 0..7) of tile+1
        if (pf) {
            #pragma unroll
            for (int p = 0; p < 2; ++p) {
                int s2 = wid * 2 + p;        // 0..31
                int rt = s2 >> 3, kc = s2 & 7;
                const float* src = x + (size_t)((tile + 1) * BM + rt * 16 + laneR) * K_DIM + kc * 32 + laneK;
                r0[2 * p]     = *(const float4*)src;
                r0[2 * p + 1] = *(const float4*)(src + 4);
            }
        }

        #pragma unroll
        for (int i = 0; i < 4; ++i) { acc[i][0] = (floatx4)0.f; acc[i][1] = (floatx4)0.f; }

        // ---- compute kc 0..7 from LDS half0(tile) ----
        #pragma unroll
        for (int kc = 0; kc < 8; ++kc) {
            bf16x8 ax[4];
            #pragma unroll
            for (int rt = 0; rt < 4; ++rt)
                ax[rt] = *(const bf16x8*)&lds[(rt * 16 + kc) * 512 + lane * 8];
            #pragma unroll
            for (int nt = 0; nt < 2; ++nt) {
                bf16x8 bw;
                if (USE_WF) {
                    int ntg = (wid << 1) + nt;
                    bw = *(const bf16x8*)(wf + (size_t)(((ntg << 4) + kc) * 64 + lane) * 8);
                } else {
                    int n = colb + (nt << 4) + laneR;
                    const float* src = w + (size_t)n * K_DIM + (kc << 5) + laneK;
                    bw = cvt8(*(const float4*)src, *(const float4*)(src + 4));
                }
                #pragma unroll
                for (int rt = 0; rt < 4; ++rt)
                    acc[rt][nt] = __builtin_amdgcn_mfma_f32_16x16x32_bf16(bw, ax[rt], acc[rt][nt], 0, 0, 0);
            }
        }

        __syncthreads();   // bar1: all waves finished reading half0(tile)

        if (pf) {
            // write half0(tile+1) into LDS (read next iteration, after bar2)
            #pragma unroll
            for (int p = 0; p < 2; ++p) {
                int s2 = wid * 2 + p;
                int rt = s2 >> 3, kc = s2 & 7;
                *(bf16x8*)&lds[(rt * 16 + kc) * 512 + lane * 8] = cvt8(r0[2 * p], r0[2 * p + 1]);
            }
            // issue global loads for half1 (kc 8..15) of tile+1
            #pragma unroll
            for (int p = 0; p < 2; ++p) {
                int s2 = wid * 2 + p;
                int rt = s2 >> 3, kc = 8 + (s2 & 7);
                const float* src = x + (size_t)((tile + 1) * BM + rt * 16 + laneR) * K_DIM + kc * 32 + laneK;
                r1[2 * p]     = *(const float4*)src;
                r1[2 * p + 1] = *(const float4*)(src + 4);
            }
        }

        // ---- compute kc 8..15 from LDS half1(tile) ----
        #pragma unroll
        for (int kc = 8; kc < 16; ++kc) {
            bf16x8 ax[4];
            #pragma unroll
            for (int rt = 0; rt < 4; ++rt)
                ax[rt] = *(const bf16x8*)&lds[(rt * 16 + kc) * 512 + lane * 8];
            #pragma unroll
            for (int nt = 0; nt < 2; ++nt) {
                bf16x8 bw;
                if (USE_WF) {
                    int ntg = (wid << 1) + nt;
                    bw = *(const bf16x8*)(wf + (size_t)(((ntg << 4) + kc) * 64 + lane) * 8);
                } else {
                    int n = colb + (nt << 4) + laneR;
                    const float* src = w + (size_t)n * K_DIM + (kc << 5) + laneK;
                    bw = cvt8(*(const float4*)src, *(const float4*)(src + 4));
                }
                #pragma unroll
                for (int rt = 0; rt < 4; ++rt)
                    acc[rt][nt] = __builtin_amdgcn_mfma_f32_16x16x32_bf16(bw, ax[rt], acc[rt][nt], 0, 0, 0);
            }
        }

        // ---- epilogue: dequant + fp32 float4 stores ----
        #pragma unroll
        for (int rt = 0; rt < 4; ++rt) {
            int m = rowb + rt * 16 + laneR;
            float xs = xscale[m];
            #pragma unroll
            for (int nt = 0; nt < 2; ++nt) {
                int nb = colb + (nt << 4) + ((lane >> 4) << 2);
                float4 wsc = *(const float4*)(wscale + nb);
                floatx4 a = acc[rt][nt];
                float4 o;
                o.x = a[0] * xs * wsc.x;
                o.y = a[1] * xs * wsc.y;
                o.z = a[2] * xs * wsc.z;
                o.w = a[3] * xs * wsc.w;
                *(float4*)(out + (size_t)m * N_DIM + nb) = o;
            }
        }

        __syncthreads();   // bar2: all waves finished reading half1(tile)

        if (pf) {
            // write half1(tile+1); its readers wait at bar1 of next iteration
            #pragma unroll
            for (int p = 0; p < 2; ++p) {
                int s2 = wid * 2 + p;
                int rt = s2 >> 3, kc = 8 + (s2 & 7);
                *(bf16x8*)&lds[(rt * 16 + kc) * 512 + lane * 8] = cvt8(r1[2 * p], r1[2 * p + 1]);
            }
        }
    }
}

extern "C" void kernel_launch(void* const* d_in, const int* in_sizes, int n_in,
                              void* d_out, int out_size, void* d_ws, size_t ws_size,
                              hipStream_t stream) {
    const float* x      = (const float*)d_in[0];
    const float* xscale = (const float*)d_in[1];
    const float* w      = (const float*)d_in[2];
    const float* wscale = (const float*)d_in[3];
    float* out          = (float*)d_out;

    const int M = in_sizes[0] / K_DIM;            // 131072
    const int ntiles = M / BM;                    // 2048
    const int nblocks = (ntiles < 256) ? ntiles : 256;
    const int tpb = (ntiles + nblocks - 1) / nblocks;   // 8

    if (ws_size >= (size_t)(N_DIM * K_DIM * sizeof(unsigned short))) {
        __bf16* wfp = (__bf16*)d_ws;
        wconv_kernel<<<dim3(64), dim3(512), 0, stream>>>(w, wfp);
        gemm_kernel<true><<<dim3(nblocks), dim3(1024), 0, stream>>>(
            x, xscale, wfp, w, wscale, out, ntiles, tpb);
    } else {
        gemm_kernel<false><<<dim3(nblocks), dim3(1024), 0, stream>>>(
            x, xscale, nullptr, w, wscale, out, ntiles, tpb);
    }
}

// Round 5
// 297.285 us; speedup vs baseline: 1.3707x; 1.3707x over previous
//
#include <hip/hip_runtime.h>
#include <hip/hip_bf16.h>
#include <stdint.h>

#define K_DIM 512
#define N_DIM 512
#define BM 64
#define CHUNK_K 128                      // fp32 k-columns per LDS chunk
#define CHUNK_FLOATS (BM * CHUNK_K)      // 8192 floats = 32 KiB

typedef __bf16 bf16x8 __attribute__((ext_vector_type(8)));
typedef float floatx4 __attribute__((ext_vector_type(4)));

__device__ __forceinline__ bf16x8 cvt8(float4 a, float4 b) {
    bf16x8 r;
    r[0] = (__bf16)a.x; r[1] = (__bf16)a.y; r[2] = (__bf16)a.z; r[3] = (__bf16)a.w;
    r[4] = (__bf16)b.x; r[5] = (__bf16)b.y; r[6] = (__bf16)b.z; r[7] = (__bf16)b.w;
    return r;
}

// Pre-convert W [N,K] fp32 -> fragment-linear bf16:
// wf[((ntg*16+kc)*64 + lane)*8 + j] = W[ntg*16+(lane&15)][kc*32+(lane>>4)*8+j]
__global__ __launch_bounds__(512) void wconv_kernel(const float* __restrict__ w,
                                                    __bf16* __restrict__ wf) {
    int t = blockIdx.x * 512 + threadIdx.x;     // 0..32767
    int lane = t & 63, slot = t >> 6;           // slot = ntg*16+kc
    int n = ((slot >> 4) << 4) + (lane & 15);
    int k = ((slot & 15) << 5) + ((lane >> 4) << 3);
    const float* src = w + (size_t)n * K_DIM + k;
    float4 f0 = *(const float4*)src;
    float4 f1 = *(const float4*)(src + 4);
    *(bf16x8*)(wf + (size_t)t * 8) = cvt8(f0, f1);
}

// stage one 64x128 fp32 chunk of x into ldsBuf via global_load_lds (4 instrs/thread).
// LDS physical layout: row-major [64][128] fp32; physical in-row byte p holds the
// source in-row byte p ^ ((row&7)<<4). Achieved with a linear LDS destination
// (wave-uniform base + lane*16) and a per-lane inverse-swizzled GLOBAL source
// address (rule #21: both-sides-or-neither; the involution is the XOR itself).
__device__ __forceinline__ void stage_chunk(const float* __restrict__ x,
                                            int rowBase, int kBase,
                                            float* ldsBuf, int wid, int lane) {
    #pragma unroll
    for (int i = 0; i < 4; ++i) {
        int sl = i * 8 + wid;                        // 0..31, wave-uniform
        int row = sl * 2 + (lane >> 5);              // 0..63
        int srcByte = ((lane & 31) * 16) ^ ((row & 7) << 4);
        const float* g = x + (size_t)(rowBase + row) * K_DIM + kBase + (srcByte >> 2);
        float* l = ldsBuf + sl * 256;                // wave-uniform LDS base (1 KiB/instr)
        __builtin_amdgcn_global_load_lds(
            (const __attribute__((address_space(1))) void*)g,
            (__attribute__((address_space(3))) void*)l, 16, 0, 0);
    }
}

// read A fragment (rt, kcl) from swizzled fp32 chunk, convert to bf16x8.
// Each 16B half is fetched at its OWN swizzled address: the swizzle XORs bits 4-6,
// so physical addresses of consecutive 16B halves are NOT contiguous for odd rows
// ((b0+16)^sw == (b0^sw)-16 when bit4 of sw is set). Round-4 bug was reading p+16.
__device__ __forceinline__ bf16x8 read_afrag(const float* ldsBuf, int rt, int kcl, int lane) {
    int row = rt * 16 + (lane & 15);
    int sw = (row & 7) << 4;
    int b0 = kcl * 128 + ((lane >> 4) << 5);         // source byte-in-row (32-aligned)
    const char* rb = (const char*)(ldsBuf + row * CHUNK_K);
    float4 fa = *(const float4*)(rb + (b0 ^ sw));
    float4 fb = *(const float4*)(rb + ((b0 + 16) ^ sw));
    return cvt8(fa, fb);
}

template <bool USE_WF>
__global__ __launch_bounds__(512, 4) void gemm_kernel(
    const float* __restrict__ x, const float* __restrict__ xscale,
    const __bf16* __restrict__ wf, const float* __restrict__ w,
    const float* __restrict__ wscale, float* __restrict__ out,
    int ntiles, int tilesPerBlock)
{
    __shared__ float lds[2 * CHUNK_FLOATS];          // 64 KiB double buffer
    const int t = threadIdx.x;
    const int lane = t & 63;
    const int wid = t >> 6;                          // 0..7
    const int laneR = lane & 15;
    const int colb = wid * 64;

    const int tile0 = blockIdx.x * tilesPerBlock;
    if (tile0 >= ntiles) return;
    const int tileEnd = (tile0 + tilesPerBlock < ntiles) ? (tile0 + tilesPerBlock) : ntiles;
    const int nChunks = (tileEnd - tile0) * 4;       // 4 chunks of K=128 per tile

    floatx4 acc[4][4];

    // prologue: issue chunk 0 loads (no wait yet — loop iter 0 waits via vmcnt)
    stage_chunk(x, tile0 * BM, 0, &lds[0], wid, lane);

    for (int c = 0; c < nChunks; ++c) {
        const int tile = tile0 + (c >> 2);

        // [A] all waves done reading buf[(c-1)&1] -> safe to overwrite it
        if (c > 0)
            asm volatile("s_waitcnt lgkmcnt(0)\n\ts_barrier" ::: "memory");

        // [B] issue next chunk's loads into the other buffer (stay in flight past barrier)
        if (c + 1 < nChunks) {
            int cn = c + 1;
            stage_chunk(x, (tile0 + (cn >> 2)) * BM, (cn & 3) * CHUNK_K,
                        &lds[(cn & 1) * CHUNK_FLOATS], wid, lane);
            // [C]+[D] my stage(c) retired (4 newest = stage(c+1) still in flight); sync all waves
            asm volatile("s_waitcnt vmcnt(4)\n\ts_barrier" ::: "memory");
        } else {
            asm volatile("s_waitcnt vmcnt(0)\n\ts_barrier" ::: "memory");
        }

        // [E] new tile -> reset accumulators
        if ((c & 3) == 0) {
            #pragma unroll
            for (int i = 0; i < 4; ++i)
                #pragma unroll
                for (int j = 0; j < 4; ++j) acc[i][j] = (floatx4)0.f;
        }

        // [F] compute 4 k32-steps from buf[c&1]
        const float* cb = &lds[(c & 1) * CHUNK_FLOATS];
        #pragma unroll
        for (int kcl = 0; kcl < 4; ++kcl) {
            const int kcg = (c & 3) * 4 + kcl;       // global k32 index 0..15
            bf16x8 ax[4];
            #pragma unroll
            for (int rt = 0; rt < 4; ++rt)
                ax[rt] = read_afrag(cb, rt, kcl, lane);
            #pragma unroll
            for (int nt = 0; nt < 4; ++nt) {
                bf16x8 bw;
                if (USE_WF) {
                    int ntg = (wid << 2) + nt;
                    bw = *(const bf16x8*)(wf + (size_t)(((ntg << 4) + kcg) * 64 + lane) * 8);
                } else {
                    int n = colb + (nt << 4) + laneR;
                    const float* src = w + (size_t)n * K_DIM + (kcg << 5) + ((lane >> 4) << 3);
                    bw = cvt8(*(const float4*)src, *(const float4*)(src + 4));
                }
                #pragma unroll
                for (int rt = 0; rt < 4; ++rt)
                    acc[rt][nt] = __builtin_amdgcn_mfma_f32_16x16x32_bf16(bw, ax[rt], acc[rt][nt], 0, 0, 0);
            }
        }

        // [G] tile finished -> dequant + fp32 float4 stores
        if ((c & 3) == 3) {
            const int rowb = tile * BM;
            #pragma unroll
            for (int rt = 0; rt < 4; ++rt) {
                int m = rowb + rt * 16 + laneR;
                float xs = xscale[m];
                #pragma unroll
                for (int nt = 0; nt < 4; ++nt) {
                    int nb = colb + (nt << 4) + ((lane >> 4) << 2);
                    float4 wsc = *(const float4*)(wscale + nb);
                    floatx4 a = acc[rt][nt];
                    float4 o;
                    o.x = a[0] * xs * wsc.x;
                    o.y = a[1] * xs * wsc.y;
                    o.z = a[2] * xs * wsc.z;
                    o.w = a[3] * xs * wsc.w;
                    *(float4*)(out + (size_t)m * N_DIM + nb) = o;
                }
            }
        }
    }
}

extern "C" void kernel_launch(void* const* d_in, const int* in_sizes, int n_in,
                              void* d_out, int out_size, void* d_ws, size_t ws_size,
                              hipStream_t stream) {
    const float* x      = (const float*)d_in[0];
    const float* xscale = (const float*)d_in[1];
    const float* w      = (const float*)d_in[2];
    const float* wscale = (const float*)d_in[3];
    float* out          = (float*)d_out;

    const int M = in_sizes[0] / K_DIM;            // 131072
    const int ntiles = M / BM;                    // 2048
    const int nblocks = (ntiles < 512) ? ntiles : 512;
    const int tpb = (ntiles + nblocks - 1) / nblocks;   // 4

    if (ws_size >= (size_t)(N_DIM * K_DIM * sizeof(unsigned short))) {
        __bf16* wfp = (__bf16*)d_ws;
        wconv_kernel<<<dim3(64), dim3(512), 0, stream>>>(w, wfp);
        gemm_kernel<true><<<dim3(nblocks), dim3(512), 0, stream>>>(
            x, xscale, wfp, w, wscale, out, ntiles, tpb);
    } else {
        gemm_kernel<false><<<dim3(nblocks), dim3(512), 0, stream>>>(
            x, xscale, nullptr, w, wscale, out, ntiles, tpb);
    }
}

// Round 6
// 233.367 us; speedup vs baseline: 1.7462x; 1.2739x over previous
//
#include <hip/hip_runtime.h>
#include <hip/hip_bf16.h>
#include <stdint.h>

#define K_DIM 512
#define N_DIM 512
#define BM 64
#define CHUNK_K 64                       // fp32 k-columns per LDS chunk
#define CHUNK_FLOATS (BM * CHUNK_K)      // 4096 floats = 16 KiB

typedef __bf16 bf16x8 __attribute__((ext_vector_type(8)));
typedef float floatx4 __attribute__((ext_vector_type(4)));

__device__ __forceinline__ bf16x8 cvt8(float4 a, float4 b) {
    bf16x8 r;
    r[0] = (__bf16)a.x; r[1] = (__bf16)a.y; r[2] = (__bf16)a.z; r[3] = (__bf16)a.w;
    r[4] = (__bf16)b.x; r[5] = (__bf16)b.y; r[6] = (__bf16)b.z; r[7] = (__bf16)b.w;
    return r;
}

// Pre-convert W [N,K] fp32 -> fragment-linear bf16:
// wf[((ntg*16+kcg)*64 + lane)*8 + j] = W[ntg*16+(lane&15)][kcg*32+(lane>>4)*8+j]
__global__ __launch_bounds__(512) void wconv_kernel(const float* __restrict__ w,
                                                    __bf16* __restrict__ wf) {
    int t = blockIdx.x * 512 + threadIdx.x;     // 0..32767
    int lane = t & 63, slot = t >> 6;           // slot = ntg*16+kcg
    int n = ((slot >> 4) << 4) + (lane & 15);
    int k = ((slot & 15) << 5) + ((lane >> 4) << 3);
    const float* src = w + (size_t)n * K_DIM + k;
    float4 f0 = *(const float4*)src;
    float4 f1 = *(const float4*)(src + 4);
    *(bf16x8*)(wf + (size_t)t * 8) = cvt8(f0, f1);
}

// stage one 64x64 fp32 chunk of x into ldsBuf via global_load_lds (2 instrs/thread).
// LDS physical layout: row-major [64][64] fp32 (256 B/row); physical in-row byte p
// holds source in-row byte p ^ ((row&7)<<4). Linear LDS dest (wave-uniform base +
// lane*16) + inverse-swizzled per-lane GLOBAL source (rule #21).
__device__ __forceinline__ void stage_chunk(const float* __restrict__ x,
                                            int rowBase, int kBase,
                                            float* ldsBuf, int wid, int lane) {
    #pragma unroll
    for (int i = 0; i < 2; ++i) {
        int sl = i * 8 + wid;                    // 0..15, wave-uniform
        int row = sl * 4 + (lane >> 4);          // 0..63
        int srcByte = ((lane & 15) << 4) ^ ((row & 7) << 4);
        const float* g = x + (size_t)(rowBase + row) * K_DIM + kBase + (srcByte >> 2);
        float* l = ldsBuf + sl * 1024 / 4;       // 1 KiB per sl, wave-uniform
        __builtin_amdgcn_global_load_lds(
            (const __attribute__((address_space(1))) void*)g,
            (__attribute__((address_space(3))) void*)l, 16, 0, 0);
    }
}

// read A fragment (row group) from swizzled fp32 chunk -> bf16x8.
// Each 16B half fetched at its OWN swizzled address (round-4 lesson).
__device__ __forceinline__ bf16x8 read_afrag(const float* ldsBuf, int mg, int rt,
                                             int kcl, int lane) {
    int row = mg * 32 + rt * 16 + (lane & 15);
    int sw = (row & 7) << 4;
    int b0 = kcl * 128 + ((lane >> 4) << 5);     // source byte-in-row, 0..224
    const char* rb = (const char*)(ldsBuf + row * CHUNK_K);
    float4 fa = *(const float4*)(rb + (b0 ^ sw));
    float4 fb = *(const float4*)(rb + ((b0 + 16) ^ sw));
    return cvt8(fa, fb);
}

// Persistent 1-block/CU pipelined GEMM. 8 waves = 2(M) x 4(N); wave tile 32x128.
// Per chunk (K=64): W fragments loaded to REGISTERS in the stage phase (older than
// next chunk's global_load_lds in the vm queue), so compute issues ZERO vm ops and
// the counted vmcnt(2) leaves only stage(c+1) in flight across the barrier.
template <bool USE_WF>
__global__ __launch_bounds__(512, 2) void gemm_kernel(
    const float* __restrict__ x, const float* __restrict__ xscale,
    const __bf16* __restrict__ wf, const float* __restrict__ w,
    const float* __restrict__ wscale, float* __restrict__ out,
    int ntiles, int tilesPerBlock)
{
    __shared__ float lds[2 * CHUNK_FLOATS];      // 32 KiB double buffer
    const int t = threadIdx.x;
    const int lane = t & 63;
    const int wid = t >> 6;                      // 0..7
    const int mg = wid >> 2;                     // 0..1  (M half)
    const int ng = wid & 3;                      // 0..3  (N quarter)
    const int laneR = lane & 15;

    const int tile0 = blockIdx.x * tilesPerBlock;
    if (tile0 >= ntiles) return;
    const int tileEnd = (tile0 + tilesPerBlock < ntiles) ? (tile0 + tilesPerBlock) : ntiles;
    const int nChunks = (tileEnd - tile0) * 8;   // 8 chunks of K=64 per tile

    floatx4 acc[2][8];
    bf16x8 wfr[8][2];

    // prologue: issue chunk 0 stage (waits resolved by iter-0 vmcnt)
    stage_chunk(x, tile0 * BM, 0, &lds[0], wid, lane);

    for (int c = 0; c < nChunks; ++c) {
        const int tile = tile0 + (c >> 3);
        const int kk = c & 7;                    // chunk-in-tile; kcg = kk*2 + kcl

        // [A] all waves done reading buf[(c-1)&1] -> safe to overwrite
        if (c > 0)
            asm volatile("s_waitcnt lgkmcnt(0)\n\ts_barrier" ::: "memory");

        // [B] W fragments for chunk c -> registers (issued BEFORE stage(c+1))
        #pragma unroll
        for (int nt = 0; nt < 8; ++nt) {
            int ntg = ng * 8 + nt;
            #pragma unroll
            for (int kcl = 0; kcl < 2; ++kcl) {
                int kcg = kk * 2 + kcl;
                if (USE_WF) {
                    wfr[nt][kcl] = *(const bf16x8*)(wf + (size_t)(((ntg << 4) + kcg) * 64 + lane) * 8);
                } else {
                    int n = (ntg << 4) + laneR;
                    const float* src = w + (size_t)n * K_DIM + (kcg << 5) + ((lane >> 4) << 3);
                    wfr[nt][kcl] = cvt8(*(const float4*)src, *(const float4*)(src + 4));
                }
            }
        }
        __builtin_amdgcn_sched_barrier(0);       // keep wf loads older than stage(c+1)

        // [C] issue next chunk's stage into the other buffer
        if (c + 1 < nChunks) {
            int cn = c + 1;
            stage_chunk(x, (tile0 + (cn >> 3)) * BM, (cn & 7) * CHUNK_K,
                        &lds[(cn & 1) * CHUNK_FLOATS], wid, lane);
            __builtin_amdgcn_sched_barrier(0);
            // wait: wf(c) + stage(c) done; stage(c+1) (2 newest) stays in flight
            asm volatile("s_waitcnt vmcnt(2)\n\ts_barrier" ::: "memory");
        } else {
            asm volatile("s_waitcnt vmcnt(0)\n\ts_barrier" ::: "memory");
        }

        // [D] new tile -> reset accumulators
        if (kk == 0) {
            #pragma unroll
            for (int i = 0; i < 2; ++i)
                #pragma unroll
                for (int j = 0; j < 8; ++j) acc[i][j] = (floatx4)0.f;
        }

        // [E] compute: 2 k32-steps, zero vm ops
        const float* cb = &lds[(c & 1) * CHUNK_FLOATS];
        #pragma unroll
        for (int kcl = 0; kcl < 2; ++kcl) {
            bf16x8 ax[2];
            #pragma unroll
            for (int rt = 0; rt < 2; ++rt)
                ax[rt] = read_afrag(cb, mg, rt, kcl, lane);
            #pragma unroll
            for (int nt = 0; nt < 8; ++nt)
                #pragma unroll
                for (int rt = 0; rt < 2; ++rt)
                    acc[rt][nt] = __builtin_amdgcn_mfma_f32_16x16x32_bf16(
                        wfr[nt][kcl], ax[rt], acc[rt][nt], 0, 0, 0);
        }

        // [F] tile finished -> dequant + fp32 float4 stores
        if (kk == 7) {
            const int rowb = tile * BM;
            #pragma unroll
            for (int rt = 0; rt < 2; ++rt) {
                int m = rowb + mg * 32 + rt * 16 + laneR;
                float xs = xscale[m];
                #pragma unroll
                for (int nt = 0; nt < 8; ++nt) {
                    int nb = ng * 128 + (nt << 4) + ((lane >> 4) << 2);
                    float4 wsc = *(const float4*)(wscale + nb);
                    floatx4 a = acc[rt][nt];
                    float4 o;
                    o.x = a[0] * xs * wsc.x;
                    o.y = a[1] * xs * wsc.y;
                    o.z = a[2] * xs * wsc.z;
                    o.w = a[3] * xs * wsc.w;
                    *(float4*)(out + (size_t)m * N_DIM + nb) = o;
                }
            }
        }
    }
}

extern "C" void kernel_launch(void* const* d_in, const int* in_sizes, int n_in,
                              void* d_out, int out_size, void* d_ws, size_t ws_size,
                              hipStream_t stream) {
    const float* x      = (const float*)d_in[0];
    const float* xscale = (const float*)d_in[1];
    const float* w      = (const float*)d_in[2];
    const float* wscale = (const float*)d_in[3];
    float* out          = (float*)d_out;

    const int M = in_sizes[0] / K_DIM;            // 131072
    const int ntiles = M / BM;                    // 2048
    const int nblocks = (ntiles < 256) ? ntiles : 256;
    const int tpb = (ntiles + nblocks - 1) / nblocks;   // 8

    if (ws_size >= (size_t)(N_DIM * K_DIM * sizeof(unsigned short))) {
        __bf16* wfp = (__bf16*)d_ws;
        wconv_kernel<<<dim3(64), dim3(512), 0, stream>>>(w, wfp);
        gemm_kernel<true><<<dim3(nblocks), dim3(512), 0, stream>>>(
            x, xscale, wfp, w, wscale, out, ntiles, tpb);
    } else {
        gemm_kernel<false><<<dim3(nblocks), dim3(512), 0, stream>>>(
            x, xscale, nullptr, w, wscale, out, ntiles, tpb);
    }
}